// Round 4
// baseline (14.121 us; speedup 1.0000x reference)
//
#include <hip/hip_runtime.h>

// out[b,i,h] = m_i * (1/denom_b) * sum_{j valid} sigmoid(zc[b,i,h] + zy[b,j,h])
// zc = z@Wc^T+bc, zy = z@Wy^T+by.
// sigmoid(a+b) = 1/(1+e^{-a}e^{-b}); E=e^{-zc} (regs), F=e^{-zy} (LDS->regs).
// Invalid j: F = 1e8 sentinel -> contribution ~1e-8; fixed 48-trip loop.
// Stage B: ALL 48 F values hoisted to registers in one batched read block
// (conflict-free broadcast ds_read_b32), then pure-VALU quad loop:
// 1/t0+1/t1+1/t2+1/t3 = (sum of triple products)/(t0t1t2t3) -> 1 rcp / 4 j.

#define LOG2E 1.4426950408889634f

constexpr int NV = 48;
constexpr int H  = 32;
constexpr int BLOCK = 512;      // 8 waves; thread = (i0 in 0..15, h in 0..31)
constexpr int WPAD = 36;        // padded W row stride (floats), 16B-aligned rows
constexpr float F_INV = 1.0e8f; // sentinel for invalid j

__global__ __launch_bounds__(BLOCK, 4)
void OptLinker_attn_kernel(const float* __restrict__ z,
                           const float* __restrict__ Wc,
                           const float* __restrict__ bc,
                           const float* __restrict__ Wy,
                           const float* __restrict__ by,
                           const int*   __restrict__ mask,
                           float* __restrict__ out)
{
    __shared__ float z_s[NV * H];       // 6 KB
    __shared__ float F_s[NV * H];       // 6 KB  e^{-zy[j,h]} (or sentinel)
    __shared__ float wc_s[H * WPAD];    // 4.5 KB
    __shared__ float wy_s[H * WPAD];    // 4.5 KB

    const int b   = blockIdx.x;
    const int tid = threadIdx.x;
    const int h   = tid & 31;           // lane's H column
    const int i0  = tid >> 5;           // 0..15; rows i0, i0+16, i0+32

    // ---- stage 0c first: mask + biases prefetch (longest dep chain) ----
    const int lane = tid & 63;
    const int mv = (lane < NV) ? mask[b * NV + lane] : 0;
    const float bcv = bc[h], byv = by[h];

    // ---- stage 0a: z tile -> LDS (float4, coalesced; 384 float4) ----
    const float4* zb4 = (const float4*)(z + (size_t)b * (NV * H));
    if (tid < (NV * H) / 4) ((float4*)z_s)[tid] = zb4[tid];

    // ---- stage 0b: W -> LDS, coalesced, one float4 per thread ----
    {
        const int q = tid & 255;                    // float4 index within matrix
        const float4 v = (tid < 256) ? ((const float4*)Wc)[q]
                                     : ((const float4*)Wy)[q];
        float* dst = (tid < 256 ? wc_s : wy_s) + (q >> 3) * WPAD + (q & 7) * 4;
        *(float4*)dst = v;                          // 16B-aligned
    }

    const unsigned long long bits = __ballot(mv != 0);

    __syncthreads();   // z_s, W LDS ready

    // ---- W row h -> registers via ds_read_b128 ----
    float4 wc_r[8], wy_r[8];
    {
        const float* wrc = wc_s + h * WPAD;
        const float* wry = wy_s + h * WPAD;
        #pragma unroll
        for (int q = 0; q < 8; ++q) {
            wc_r[q] = *(const float4*)(wrc + q * 4);
            wy_r[q] = *(const float4*)(wry + q * 4);
        }
    }

    // ---- stage A: zc, zy for 3 rows; E in regs, F (or sentinel) to LDS ----
    float E[3];
    #pragma unroll
    for (int it = 0; it < 3; ++it) {
        const int i = i0 + it * 16;
        float accC = bcv, accY = byv;
        const float4* zr = (const float4*)(z_s + i * H);
        #pragma unroll
        for (int q = 0; q < 8; ++q) {
            const float4 zv = zr[q];   // broadcast ds_read_b128
            accC = fmaf(zv.x, wc_r[q].x, accC);
            accC = fmaf(zv.y, wc_r[q].y, accC);
            accC = fmaf(zv.z, wc_r[q].z, accC);
            accC = fmaf(zv.w, wc_r[q].w, accC);
            accY = fmaf(zv.x, wy_r[q].x, accY);
            accY = fmaf(zv.y, wy_r[q].y, accY);
            accY = fmaf(zv.z, wy_r[q].z, accY);
            accY = fmaf(zv.w, wy_r[q].w, accY);
        }
        E[it] = __builtin_amdgcn_exp2f(-accC * LOG2E);           // e^{-zc}
        const bool vi = (bits >> i) & 1ull;
        F_s[i * H + h] = vi ? __builtin_amdgcn_exp2f(-accY * LOG2E) : F_INV;
    }
    __syncthreads();   // F_s ready

    // ---- stage B0: hoist ALL F into registers (batched, conflict-free) ----
    float f_r[NV];
    #pragma unroll
    for (int j = 0; j < NV; ++j) f_r[j] = F_s[j * H + h];

    // ---- stage B1: pure-VALU fixed loop, 4-way rational combine ----
    float acc[3] = {0.f, 0.f, 0.f};
    #pragma unroll
    for (int jq = 0; jq < NV / 4; ++jq) {
        const float f0 = f_r[4 * jq + 0];
        const float f1 = f_r[4 * jq + 1];
        const float f2 = f_r[4 * jq + 2];
        const float f3 = f_r[4 * jq + 3];
        #pragma unroll
        for (int it = 0; it < 3; ++it) {
            const float Ei = E[it];
            const float t0 = fmaf(Ei, f0, 1.0f);
            const float t1 = fmaf(Ei, f1, 1.0f);
            const float t2 = fmaf(Ei, f2, 1.0f);
            const float t3 = fmaf(Ei, f3, 1.0f);
            const float p01 = t0 * t1, p23 = t2 * t3;
            const float den = p01 * p23;
            const float num = fmaf(t0 + t1, p23, (t2 + t3) * p01);
            acc[it] = fmaf(num, __builtin_amdgcn_rcpf(den), acc[it]);
        }
    }

    // ---- epilogue ----
    const int nvalid = __popcll(bits);
    const float rden = __builtin_amdgcn_rcpf((float)nvalid);
    float* ob = out + (size_t)b * (NV * H);
    #pragma unroll
    for (int it = 0; it < 3; ++it) {
        const int i = i0 + it * 16;
        ob[i * H + h] = ((bits >> i) & 1ull) ? acc[it] * rden : 0.0f;
    }
}

extern "C" void kernel_launch(void* const* d_in, const int* in_sizes, int n_in,
                              void* d_out, int out_size, void* d_ws, size_t ws_size,
                              hipStream_t stream) {
    const float* z    = (const float*)d_in[0];
    const float* Wc   = (const float*)d_in[1];
    const float* bc   = (const float*)d_in[2];
    const float* Wy   = (const float*)d_in[3];
    const float* by   = (const float*)d_in[4];
    const int*   mask = (const int*)d_in[5];
    float* out = (float*)d_out;

    const int ngraph = in_sizes[0] / (NV * H);   // 512
    OptLinker_attn_kernel<<<ngraph, BLOCK, 0, stream>>>(z, Wc, bc, Wy, by, mask, out);
}